// Round 3
// baseline (406.644 us; speedup 1.0000x reference)
//
#include <hip/hip_runtime.h>
#include <hip/hip_bf16.h>

// Problem constants
#define KTOT   268203          // 3*299*299
#define MROWS  256             // B*T = 4*64
#define NCOLS  512             // D1
#define HDIM   28
#define NSTEPS 8382            // ceil(KTOT/32); padded K = 268224
#define CHUNKS_PER_STEP 1024   // 256 rows x 4 k-octets, 16B each

typedef __attribute__((ext_vector_type(4))) float  f32x4;
typedef __attribute__((ext_vector_type(8))) __bf16 bf16x8;
typedef __attribute__((ext_vector_type(8))) unsigned short u16x8;

// -------------------------------------------------------------------------
// Kernel 0: pre-tile x -> bf16 chunks in gemm consumption order.
// Chunk g = s*1024 + c ; c = row*4 + oc ; stored k-octet ko = oc ^ ((row>>1)&3)
// (XOR placement makes gemm's fragment ds_read_b128 2-way = conflict-free).
// Zero-pads k in [KTOT, 268224).
// -------------------------------------------------------------------------
__global__ __launch_bounds__(256) void xprep_kernel(
    const float* __restrict__ x, __hip_bfloat16* __restrict__ xb)
{
    const size_t g = (size_t)blockIdx.x * 256 + threadIdx.x;
    if (g >= (size_t)NSTEPS * CHUNKS_PER_STEP) return;
    const int s   = (int)(g >> 10);
    const int c   = (int)(g & 1023);
    const int row = c >> 2;
    const int oc  = c & 3;
    const int ko  = oc ^ ((row >> 1) & 3);
    const long k0 = (long)s * 32 + ko * 8;
    const float* src = x + (size_t)row * KTOT;
    union { u16x8 v; __hip_bfloat16 h[8]; } o;
    #pragma unroll
    for (int j = 0; j < 8; ++j) {
        const long k = k0 + j;
        o.h[j] = __float2bfloat16(k < KTOT ? src[k] : 0.f);
    }
    *(u16x8*)(xb + g * 8) = o.v;
}

// -------------------------------------------------------------------------
// Kernel 1: split-K GEMM  part[ks] = x[256 x Kchunk] * W1[Kchunk x 128cols]
// BM=256, BN=128, BK=32. 512 threads = 8 waves (4x2 of 64x64 tiles).
// A: global_load_lds dwordx4 from pre-tiled bf16 x (2 instr/thread/step).
// B: 8 consecutive-k fp32 loads -> cvt -> one aligned ds_write_b128.
// Double-buffered LDS, ONE barrier per K-step, loads issued one step ahead.
// XCD swizzle: 4 N-tile sharers of an x-chunk land on the same XCD's L2.
// -------------------------------------------------------------------------
__global__ __launch_bounds__(512, 4) void gemm1_kernel(
    const __hip_bfloat16* __restrict__ xb, const float* __restrict__ W1,
    float* __restrict__ part, int steps_per, int nks)
{
    __shared__ __align__(16) __hip_bfloat16 Albuf[2][CHUNKS_PER_STEP * 8]; // 2x16KB
    __shared__ __align__(16) __hip_bfloat16 Blds[2][128][40];              // 2x10KB (pad 40)

    const int tid  = threadIdx.x;
    const int lane = tid & 63;
    const int w    = tid >> 6;
    const int wm   = w >> 1;                 // 0..3 : wave row (64 rows)
    const int wn   = w & 1;                  // 0..1 : wave col (64 cols)

    // block-id swizzle: id = (ks&7) + 8*(bx + 4*(ks>>3))  -> invert
    int bx, ks;
    {
        const int id = blockIdx.x;
        if ((nks & 7) == 0) {
            const int xcd  = id & 7;
            const int rest = id >> 3;
            bx = rest & 3;
            ks = ((rest >> 2) << 3) | xcd;
        } else {
            bx = id & 3;
            ks = id >> 2;
        }
    }
    const int bcol = bx * 128;

    const int bc  = tid & 127;               // B col 0..127
    const int bkg = tid >> 7;                // B k-octet 0..3

    f32x4 acc[4][4];
    #pragma unroll
    for (int i = 0; i < 4; ++i)
        #pragma unroll
        for (int j = 0; j < 4; ++j)
            acc[i][j] = (f32x4){0.f, 0.f, 0.f, 0.f};

    const int s0 = ks * steps_per;
    int s1 = s0 + steps_per;
    if (s1 > NSTEPS) s1 = NSTEPS;

    auto issueA = [&](int s, int buf) {
        #pragma unroll
        for (int i = 0; i < 2; ++i) {
            const __hip_bfloat16* gp = xb + ((size_t)s * CHUNKS_PER_STEP + i * 512 + tid) * 8;
            __hip_bfloat16* lp = &Albuf[buf][(size_t)(i * 512 + w * 64) * 8];
            __builtin_amdgcn_global_load_lds(
                (const __attribute__((address_space(1))) unsigned int*)(const void*)gp,
                (__attribute__((address_space(3))) unsigned int*)(void*)lp, 16, 0, 0);
        }
    };

    auto loadB = [&](int s, float* breg) {
        const long kb = (long)s * 32 + bkg * 8;
        if (kb + 8 <= KTOT) {
            #pragma unroll
            for (int j = 0; j < 8; ++j)
                breg[j] = W1[(size_t)(kb + j) * NCOLS + bcol + bc];
        } else {
            #pragma unroll
            for (int j = 0; j < 8; ++j) {
                const long kk = kb + j;
                breg[j] = (kk < KTOT) ? W1[(size_t)kk * NCOLS + bcol + bc] : 0.f;
            }
        }
    };

    auto writeB = [&](const float* breg, int buf) {
        union { bf16x8 v; __hip_bfloat16 h[8]; } p;
        #pragma unroll
        for (int j = 0; j < 8; ++j) p.h[j] = __float2bfloat16(breg[j]);
        *(bf16x8*)&Blds[buf][bc][bkg * 8] = p.v;
    };

    auto compute = [&](int buf) {
        const int rc  = lane & 15;
        const int ko  = lane >> 4;
        const int swz = (rc >> 1) & 3;       // == ((row>>1)&3) for all mi
        const int abase = (wm * 64 + rc) * 32 + (ko ^ swz) * 8;   // elems
        bf16x8 af[4], bq[4];
        #pragma unroll
        for (int mi = 0; mi < 4; ++mi)
            af[mi] = *(const bf16x8*)&Albuf[buf][abase + mi * 512];
        #pragma unroll
        for (int ni = 0; ni < 4; ++ni)
            bq[ni] = *(const bf16x8*)&Blds[buf][wn * 64 + ni * 16 + rc][ko * 8];
        #pragma unroll
        for (int mi = 0; mi < 4; ++mi)
            #pragma unroll
            for (int ni = 0; ni < 4; ++ni)
                acc[mi][ni] = __builtin_amdgcn_mfma_f32_16x16x32_bf16(
                    af[mi], bq[ni], acc[mi][ni], 0, 0, 0);
    };

    if (s0 < s1) {
        float breg[8];
        // prologue: stage step s0 into buffer 0
        issueA(s0, 0);
        loadB(s0, breg);
        writeB(breg, 0);
        __syncthreads();                 // drains A-lds loads too
        int buf = 0;
        for (int s = s0; s < s1; ++s) {
            const int nb = buf ^ 1;
            const bool pf = (s + 1 < s1);
            if (pf) { issueA(s + 1, nb); loadB(s + 1, breg); }  // in flight across MFMA
            compute(buf);
            if (pf) writeB(breg, nb);    // waits only on this step's B loads
            __syncthreads();
            buf = nb;
        }
    }

    // store partials; C/D layout: col = lane&15, row = (lane>>4)*4 + reg
    float* outp = part + (size_t)ks * MROWS * NCOLS;
    #pragma unroll
    for (int mi = 0; mi < 4; ++mi) {
        const int r0 = wm * 64 + mi * 16 + ((lane >> 4) * 4);
        #pragma unroll
        for (int ni = 0; ni < 4; ++ni) {
            const int c = bcol + wn * 64 + ni * 16 + (lane & 15);
            #pragma unroll
            for (int j = 0; j < 4; ++j)
                outp[(size_t)(r0 + j) * NCOLS + c] = acc[mi][ni][j];
        }
    }
}

// -------------------------------------------------------------------------
// Kernel 2: reduce split-K partials + b1 + relu -> h1 (LDS) -> u = h1@Wi
// -------------------------------------------------------------------------
__global__ __launch_bounds__(512) void reduce_u_kernel(
    const float* __restrict__ part, const float* __restrict__ b1,
    const float* __restrict__ Wi, float* __restrict__ u, int nks)
{
    __shared__ float h1[NCOLS];
    __shared__ f32x4 red[4][128];
    const int row = blockIdx.x;
    const int tid = threadIdx.x;
    const int c4  = tid & 127;
    const int kk  = tid >> 7;

    f32x4 sum = (f32x4){0.f, 0.f, 0.f, 0.f};
    for (int k = kk; k < nks; k += 4)
        sum += *(const f32x4*)&part[((size_t)k * MROWS + row) * NCOLS + c4 * 4];
    red[kk][c4] = sum;
    __syncthreads();

    if (tid < 128) {
        f32x4 t = red[0][tid] + red[1][tid] + red[2][tid] + red[3][tid];
        const f32x4 bb = *(const f32x4*)&b1[tid * 4];
        t += bb;
        #pragma unroll
        for (int j = 0; j < 4; ++j) h1[tid * 4 + j] = fmaxf(t[j], 0.f);
    }
    __syncthreads();

    const int wv = tid >> 6, lane = tid & 63;
    #pragma unroll
    for (int hh = 0; hh < 4; ++hh) {
        const int h = wv * 4 + hh;
        if (h < HDIM) {
            float p = 0.f;
            #pragma unroll
            for (int dd = 0; dd < 8; ++dd) {
                const int d = lane + dd * 64;
                p += h1[d] * Wi[d * HDIM + h];
            }
            #pragma unroll
            for (int off = 32; off; off >>= 1) p += __shfl_down(p, off);
            if (lane == 0) u[row * HDIM + h] = p;
        }
    }
}

// -------------------------------------------------------------------------
// Kernel 3: LTC recurrence (T=64, fp32, exact reference semantics) + head
// -------------------------------------------------------------------------
__global__ __launch_bounds__(64) void recur_kernel(
    const float* __restrict__ u, const float* __restrict__ Wr,
    const float* __restrict__ br, const float* __restrict__ Av,
    const float* __restrict__ tau, const float* __restrict__ W2,
    const float* __restrict__ b2, float* __restrict__ out)
{
    const int b = blockIdx.x;
    const int j = threadIdx.x;
    const bool act = j < HDIM;
    const int jj = act ? j : 0;

    float wr[HDIM];
    #pragma unroll
    for (int i = 0; i < HDIM; ++i) wr[i] = act ? Wr[i * HDIM + jj] : 0.f;
    const float brj = act ? br[jj] : 0.f;
    const float Aj  = act ? Av[jj] : 0.f;
    const float itj = act ? (1.f / tau[jj]) : 0.f;

    float uv[64];
    #pragma unroll
    for (int t = 0; t < 64; ++t)
        uv[t] = act ? u[(b * 64 + t) * HDIM + jj] : 0.f;

    float h = 0.f;
    #pragma unroll
    for (int t = 0; t < 64; ++t) {
        float a = uv[t] + brj;
        #pragma unroll
        for (int i = 0; i < HDIM; ++i)
            a += __shfl(h, i) * wr[i];
        const float ft = 1.f / (1.f + expf(-a));
        const float hn = (h + ft * Aj) / (1.f + itj + ft);
        h = act ? hn : 0.f;
    }

    const float r  = act ? fmaxf(h, 0.f) : 0.f;
    float p0 = act ? r * W2[jj * 2 + 0] : 0.f;
    float p1 = act ? r * W2[jj * 2 + 1] : 0.f;
    #pragma unroll
    for (int off = 32; off; off >>= 1) {
        p0 += __shfl_down(p0, off);
        p1 += __shfl_down(p1, off);
    }
    if (j == 0) {
        out[b * 2 + 0] = 1.f / (1.f + expf(-(p0 + b2[0])));
        out[b * 2 + 1] = 1.f / (1.f + expf(-(p1 + b2[1])));
    }
}

// -------------------------------------------------------------------------
extern "C" void kernel_launch(void* const* d_in, const int* in_sizes, int n_in,
                              void* d_out, int out_size, void* d_ws, size_t ws_size,
                              hipStream_t stream)
{
    (void)in_sizes; (void)n_in; (void)out_size;
    const float* x   = (const float*)d_in[0];
    const float* W1  = (const float*)d_in[1];
    const float* b1  = (const float*)d_in[2];
    const float* Wi  = (const float*)d_in[3];
    const float* Wr  = (const float*)d_in[4];
    const float* br  = (const float*)d_in[5];
    const float* Av  = (const float*)d_in[6];
    const float* tau = (const float*)d_in[7];
    const float* W2  = (const float*)d_in[8];
    const float* b2  = (const float*)d_in[9];
    float* out = (float*)d_out;

    const size_t n_chunks = (size_t)NSTEPS * CHUNKS_PER_STEP;   // 8,583,168
    const size_t xb_bytes = n_chunks * 16;                      // 137,330,688
    __hip_bfloat16* xb = (__hip_bfloat16*)d_ws;
    float* part = (float*)((char*)d_ws + xb_bytes);

    const size_t per_split = (size_t)MROWS * NCOLS * sizeof(float);   // 512 KiB
    long kmax = ((long)ws_size - (long)xb_bytes - 65536) / (long)per_split;
    int nks = 128;
    if (kmax < 128) {
        nks = (int)(kmax & ~7L);
        if (nks < 1) nks = 1;
    }
    const int steps_per = (NSTEPS + nks - 1) / nks;
    float* u = part + (size_t)nks * MROWS * NCOLS;

    xprep_kernel<<<(int)(n_chunks / 256), 256, 0, stream>>>(x, xb);
    gemm1_kernel<<<dim3(4 * nks), 512, 0, stream>>>(xb, W1, part, steps_per, nks);
    reduce_u_kernel<<<dim3(MROWS), 512, 0, stream>>>(part, b1, Wi, u, nks);
    recur_kernel<<<dim3(4), 64, 0, stream>>>(u, Wr, br, Av, tau, W2, b2, out);
}

// Round 4
// 274.508 us; speedup vs baseline: 1.4814x; 1.4814x over previous
//
#include <hip/hip_runtime.h>
#include <hip/hip_bf16.h>

// Problem constants
#define KTOT   268203          // 3*299*299 (odd -> x rows only 4B-aligned)
#define MROWS  256             // B*T = 4*64
#define NCOLS  512             // D1
#define HDIM   28
#define NSTEPS 8382            // ceil(KTOT/32); step 8381 is partial (11 valid k)
#define FSTEP  8381            // number of FULL 32-k steps

typedef __attribute__((ext_vector_type(4))) float  f32x4;
typedef __attribute__((ext_vector_type(8))) __bf16 bf16x8;

static __device__ inline bf16x8 pack8(const float* f) {
    union { bf16x8 v; __hip_bfloat16 h[8]; } u;
    #pragma unroll
    for (int j = 0; j < 8; ++j) u.h[j] = __float2bfloat16(f[j]);
    return u.v;
}

// -------------------------------------------------------------------------
// Kernel 1: split-K GEMM, single-pass fp32 inputs, counted-vmcnt pipeline.
// BM=256, BN=128, BK=32; 512 thr = 8 waves (4x2 of 64x64 output tiles).
// Per step: 18 vmem ops/wave (A: 16 dword global_load_lds, source-swizzled;
// B: 2 dwordx4 global_load_lds). 3 LDS buffers, depth-2 prefetch, one raw
// s_barrier per step, s_waitcnt vmcnt(18) -> loads stay in flight across
// barriers (never drained mid-loop). fp32->bf16 cvt at fragment read.
// -------------------------------------------------------------------------
__global__ __launch_bounds__(512, 2) void gemm1_kernel(
    const float* __restrict__ x, const float* __restrict__ W1,
    float* __restrict__ part, int steps_per, int nks)
{
    __shared__ __align__(16) float Albuf[3][MROWS * 32];   // 3 x 32 KB
    __shared__ __align__(16) float Bbuf[3][32 * 128];      // 3 x 16 KB

    const int tid  = threadIdx.x;
    const int lane = tid & 63;
    const int w    = tid >> 6;
    const int wm   = w >> 1;                 // 0..3 : wave row (64 rows)
    const int wn   = w & 1;                  // 0..1 : wave col (64 cols)

    // block-id swizzle: sharers of one ks land on the same XCD
    int bx, ks;
    {
        const int id = blockIdx.x;
        if ((nks & 7) == 0) {
            const int xcd  = id & 7;
            const int rest = id >> 3;
            bx = rest & 3;
            ks = ((rest >> 2) << 3) | xcd;
        } else {
            bx = id & 3;
            ks = id >> 2;
        }
    }
    const int bcol = bx * 128;

    // ---- per-lane constant source offsets ----
    // A: lane covers (row = 16*i + 2w + dlt, float m of the 32-float span),
    //    stored at LDS slot sig = m>>2; logical k-group g = sig ^ (row&7).
    const int dlt = lane >> 5;               // 0/1
    const int m   = lane & 31;
    const int rw7 = (2 * w + dlt) & 7;       // == row&7 for every instr i
    const int ag  = (m >> 2) ^ rw7;          // logical k-group this lane fetches
    const size_t a_off = (size_t)(2 * w + dlt) * KTOT + ag * 4 + (m & 3);
    // B: lane covers k = 16*i + 2w + dlt, col-quad colq = lane&31
    const size_t b_off = (size_t)(2 * w + dlt) * NCOLS + bcol + (size_t)(m) * 4 / 4 * 0 + (lane & 31) * 4;

    f32x4 acc[4][4];
    #pragma unroll
    for (int i = 0; i < 4; ++i)
        #pragma unroll
        for (int j = 0; j < 4; ++j)
            acc[i][j] = (f32x4){0.f, 0.f, 0.f, 0.f};

    const int s0 = ks * steps_per;
    int s1 = s0 + steps_per;
    if (s1 > NSTEPS) s1 = NSTEPS;

    auto issue_step = [&](int s, int buf) {
        // A: 16 x dword (4B) -> LDS [row][32] fp32, source-swizzled
        const float* ap = x + a_off + (size_t)s * 32;
        #pragma unroll
        for (int i = 0; i < 16; ++i) {
            const float* gp = ap + (size_t)i * 16 * KTOT;
            char* lp = (char*)&Albuf[buf][0] + (i * 8 + w) * 256;   // wave-uniform
            __builtin_amdgcn_global_load_lds(
                (const __attribute__((address_space(1))) unsigned int*)(const void*)gp,
                (__attribute__((address_space(3))) unsigned int*)(void*)lp, 4, 0, 0);
        }
        // B: 2 x dwordx4 -> LDS [k][128] fp32, linear
        const float* bp = W1 + b_off + (size_t)s * 32 * NCOLS;
        #pragma unroll
        for (int i = 0; i < 2; ++i) {
            const float* gp = bp + (size_t)i * 16 * NCOLS;
            char* lp = (char*)&Bbuf[buf][0] + (i * 512 + w * 64) * 16;  // wave-uniform
            __builtin_amdgcn_global_load_lds(
                (const __attribute__((address_space(1))) unsigned int*)(const void*)gp,
                (__attribute__((address_space(3))) unsigned int*)(void*)lp, 16, 0, 0);
        }
    };

    auto compute = [&](int buf) {
        const int rc = lane & 15, ko = lane >> 4;
        // B fragments: 8 strided b32 reads per frag, cvt -> bf16x8
        bf16x8 bq[4];
        #pragma unroll
        for (int ni = 0; ni < 4; ++ni) {
            const int colL = wn * 64 + ni * 16 + rc;
            float bf[8];
            #pragma unroll
            for (int j = 0; j < 8; ++j)
                bf[j] = Bbuf[buf][(ko * 8 + j) * 128 + colL];
            bq[ni] = pack8(bf);
        }
        // A fragments: two swizzled b128 reads per frag (slots sig, sig^1)
        const int soff = ((2 * ko) ^ (rc & 7)) * 16;   // row&7 == rc&7 here
        #pragma unroll
        for (int mi = 0; mi < 4; ++mi) {
            const int ab = (wm * 64 + mi * 16 + rc) * 128;   // row byte base
            float afv[8];
            *(f32x4*)&afv[0] = *(const f32x4*)((const char*)&Albuf[buf][0] + ab + soff);
            *(f32x4*)&afv[4] = *(const f32x4*)((const char*)&Albuf[buf][0] + ab + (soff ^ 16));
            const bf16x8 af = pack8(afv);
            #pragma unroll
            for (int ni = 0; ni < 4; ++ni)
                acc[mi][ni] = __builtin_amdgcn_mfma_f32_16x16x32_bf16(
                    af, bq[ni], acc[mi][ni], 0, 0, 0);
        }
    };

    // ---- pipelined main loop over FULL steps ----
    const int s1f  = (s1 < FSTEP) ? s1 : FSTEP;
    const int nfull = s1f - s0;
    if (nfull > 0) {
        issue_step(s0, 0);
        if (nfull > 1) issue_step(s0 + 1, 1);
        for (int t = 0; t < nfull; ++t) {
            if (t + 1 < nfull) { asm volatile("s_waitcnt vmcnt(18)" ::: "memory"); }
            else               { asm volatile("s_waitcnt vmcnt(0)"  ::: "memory"); }
            __builtin_amdgcn_s_barrier();
            __builtin_amdgcn_sched_barrier(0);
            compute(t % 3);
            if (t + 2 < nfull) issue_step(s0 + t + 2, (t + 2) % 3);
        }
    }

    // ---- tail: the single partial step (only the last split owns it) ----
    if (s1 > FSTEP) {
        const int buf = nfull % 3;   // differs from (nfull-1)%3 -> no hazard
        {   // A: guarded reg-staged, swizzled ds_write
            const int arow0 = tid >> 5, ak = tid & 31;
            const int gg = ak >> 2, jj = ak & 3;
            #pragma unroll
            for (int i = 0; i < 16; ++i) {
                const int row = arow0 + i * 16;
                const float v = (ak < (KTOT - FSTEP * 32))
                    ? x[(size_t)row * KTOT + (size_t)FSTEP * 32 + ak] : 0.f;
                Albuf[buf][row * 32 + (gg ^ (row & 7)) * 4 + jj] = v;
            }
        }
        {   // B: guarded
            const int bc2 = tid & 127, bkg2 = tid >> 7;
            #pragma unroll
            for (int j = 0; j < 8; ++j) {
                const int k = bkg2 * 8 + j;
                const float v = (k < (KTOT - FSTEP * 32))
                    ? W1[(size_t)(FSTEP * 32 + k) * NCOLS + bcol + bc2] : 0.f;
                Bbuf[buf][k * 128 + bc2] = v;
            }
        }
        __syncthreads();
        compute(buf);
    }

    // store partials; C/D layout: col = lane&15, row = (lane>>4)*4 + reg
    float* outp = part + (size_t)ks * MROWS * NCOLS;
    #pragma unroll
    for (int mi = 0; mi < 4; ++mi) {
        const int r0 = wm * 64 + mi * 16 + ((lane >> 4) * 4);
        #pragma unroll
        for (int ni = 0; ni < 4; ++ni) {
            const int c = bcol + wn * 64 + ni * 16 + (lane & 15);
            #pragma unroll
            for (int j = 0; j < 4; ++j)
                outp[(size_t)(r0 + j) * NCOLS + c] = acc[mi][ni][j];
        }
    }
}

// -------------------------------------------------------------------------
// Kernel 2: reduce split-K partials + b1 + relu -> h1 (LDS) -> u = h1@Wi
// -------------------------------------------------------------------------
__global__ __launch_bounds__(512) void reduce_u_kernel(
    const float* __restrict__ part, const float* __restrict__ b1,
    const float* __restrict__ Wi, float* __restrict__ u, int nks)
{
    __shared__ float h1[NCOLS];
    __shared__ f32x4 red[4][128];
    const int row = blockIdx.x;
    const int tid = threadIdx.x;
    const int c4  = tid & 127;
    const int kk  = tid >> 7;

    f32x4 sum = (f32x4){0.f, 0.f, 0.f, 0.f};
    for (int k = kk; k < nks; k += 4)
        sum += *(const f32x4*)&part[((size_t)k * MROWS + row) * NCOLS + c4 * 4];
    red[kk][c4] = sum;
    __syncthreads();

    if (tid < 128) {
        f32x4 t = red[0][tid] + red[1][tid] + red[2][tid] + red[3][tid];
        const f32x4 bb = *(const f32x4*)&b1[tid * 4];
        t += bb;
        #pragma unroll
        for (int j = 0; j < 4; ++j) h1[tid * 4 + j] = fmaxf(t[j], 0.f);
    }
    __syncthreads();

    const int wv = tid >> 6, lane = tid & 63;
    #pragma unroll
    for (int hh = 0; hh < 4; ++hh) {
        const int h = wv * 4 + hh;
        if (h < HDIM) {
            float p = 0.f;
            #pragma unroll
            for (int dd = 0; dd < 8; ++dd) {
                const int d = lane + dd * 64;
                p += h1[d] * Wi[d * HDIM + h];
            }
            #pragma unroll
            for (int off = 32; off; off >>= 1) p += __shfl_down(p, off);
            if (lane == 0) u[row * HDIM + h] = p;
        }
    }
}

// -------------------------------------------------------------------------
// Kernel 3: LTC recurrence (T=64, fp32, exact reference semantics) + head
// -------------------------------------------------------------------------
__global__ __launch_bounds__(64) void recur_kernel(
    const float* __restrict__ u, const float* __restrict__ Wr,
    const float* __restrict__ br, const float* __restrict__ Av,
    const float* __restrict__ tau, const float* __restrict__ W2,
    const float* __restrict__ b2, float* __restrict__ out)
{
    const int b = blockIdx.x;
    const int j = threadIdx.x;
    const bool act = j < HDIM;
    const int jj = act ? j : 0;

    float wr[HDIM];
    #pragma unroll
    for (int i = 0; i < HDIM; ++i) wr[i] = act ? Wr[i * HDIM + jj] : 0.f;
    const float brj = act ? br[jj] : 0.f;
    const float Aj  = act ? Av[jj] : 0.f;
    const float itj = act ? (1.f / tau[jj]) : 0.f;

    float uv[64];
    #pragma unroll
    for (int t = 0; t < 64; ++t)
        uv[t] = act ? u[(b * 64 + t) * HDIM + jj] : 0.f;

    float h = 0.f;
    #pragma unroll
    for (int t = 0; t < 64; ++t) {
        float a = uv[t] + brj;
        #pragma unroll
        for (int i = 0; i < HDIM; ++i)
            a += __shfl(h, i) * wr[i];
        const float ft = 1.f / (1.f + expf(-a));
        const float hn = (h + ft * Aj) / (1.f + itj + ft);
        h = act ? hn : 0.f;
    }

    const float r  = act ? fmaxf(h, 0.f) : 0.f;
    float p0 = act ? r * W2[jj * 2 + 0] : 0.f;
    float p1 = act ? r * W2[jj * 2 + 1] : 0.f;
    #pragma unroll
    for (int off = 32; off; off >>= 1) {
        p0 += __shfl_down(p0, off);
        p1 += __shfl_down(p1, off);
    }
    if (j == 0) {
        out[b * 2 + 0] = 1.f / (1.f + expf(-(p0 + b2[0])));
        out[b * 2 + 1] = 1.f / (1.f + expf(-(p1 + b2[1])));
    }
}

// -------------------------------------------------------------------------
extern "C" void kernel_launch(void* const* d_in, const int* in_sizes, int n_in,
                              void* d_out, int out_size, void* d_ws, size_t ws_size,
                              hipStream_t stream)
{
    (void)in_sizes; (void)n_in; (void)out_size;
    const float* x   = (const float*)d_in[0];
    const float* W1  = (const float*)d_in[1];
    const float* b1  = (const float*)d_in[2];
    const float* Wi  = (const float*)d_in[3];
    const float* Wr  = (const float*)d_in[4];
    const float* br  = (const float*)d_in[5];
    const float* Av  = (const float*)d_in[6];
    const float* tau = (const float*)d_in[7];
    const float* W2  = (const float*)d_in[8];
    const float* b2  = (const float*)d_in[9];
    float* out = (float*)d_out;

    // nks = 64 -> grid 256 blocks = 1 per CU (LDS 144KB forces 1/CU anyway)
    const size_t per_split = (size_t)MROWS * NCOLS * sizeof(float);   // 512 KiB
    int nks = 64;
    while (nks > 8 && (size_t)nks * per_split + (1 << 16) > ws_size) nks -= 8;
    const int steps_per = (NSTEPS + nks - 1) / nks;

    float* part = (float*)d_ws;
    float* u    = part + (size_t)nks * MROWS * NCOLS;

    gemm1_kernel<<<dim3(4 * nks), 512, 0, stream>>>(x, W1, part, steps_per, nks);
    reduce_u_kernel<<<dim3(MROWS), 512, 0, stream>>>(part, b1, Wi, u, nks);
    recur_kernel<<<dim3(4), 64, 0, stream>>>(u, Wr, br, Av, tau, W2, b2, out);
}

// Round 5
// 269.721 us; speedup vs baseline: 1.5076x; 1.0177x over previous
//
#include <hip/hip_runtime.h>
#include <hip/hip_bf16.h>

// Problem constants
#define KTOT   268203          // 3*299*299 (odd -> x rows only 4B-aligned)
#define MROWS  256             // B*T = 4*64
#define NCOLS  512             // D1
#define HDIM   28
#define NSTEPS 8382            // ceil(KTOT/32); step 8381 is partial (11 valid k)
#define FSTEP  8381            // number of FULL 32-k steps

typedef __attribute__((ext_vector_type(4))) float  f32x4;
typedef __attribute__((ext_vector_type(8))) __bf16 bf16x8;

#define AUX_NT 2   // cpol NT bit (no L2 allocate) for run-once streams

static __device__ inline bf16x8 pack8(const float* f) {
    union { bf16x8 v; __hip_bfloat16 h[8]; } u;
    #pragma unroll
    for (int j = 0; j < 8; ++j) u.h[j] = __float2bfloat16(f[j]);
    return u.v;
}

// -------------------------------------------------------------------------
// Kernel 1: split-K GEMM, single-pass fp32 inputs, counted-vmcnt pipeline.
// BM=256, BN=128, BK=32; 512 thr = 8 waves (4x2 of 64x64 output tiles).
// A: 16 dword global_load_lds (source-swizzled), normal caching (4-way
//    reuse across column blocks on the same XCD).
// B: 2 dwordx4 global_load_lds, NT (W1 is read exactly once chip-wide; keep
//    it out of L2 so it can't evict the shared A chunks -> A dedup works).
// 3 LDS buffers, depth-2 prefetch, one raw s_barrier per step,
// s_waitcnt vmcnt(18) -> next step's loads stay in flight across barriers.
// -------------------------------------------------------------------------
__global__ __launch_bounds__(512, 2) void gemm1_kernel(
    const float* __restrict__ x, const float* __restrict__ W1,
    float* __restrict__ part, int steps_per, int nks)
{
    __shared__ __align__(16) float Albuf[3][MROWS * 32];   // 3 x 32 KB
    __shared__ __align__(16) float Bbuf[3][32 * 128];      // 3 x 16 KB

    const int tid  = threadIdx.x;
    const int lane = tid & 63;
    const int w    = tid >> 6;
    const int wm   = w >> 1;                 // 0..3 : wave row (64 rows)
    const int wn   = w & 1;                  // 0..1 : wave col (64 cols)

    // block-id swizzle: sharers of one ks land on the same XCD
    int bx, ks;
    {
        const int id = blockIdx.x;
        if ((nks & 7) == 0) {
            const int xcd  = id & 7;
            const int rest = id >> 3;
            bx = rest & 3;
            ks = ((rest >> 2) << 3) | xcd;
        } else {
            bx = id & 3;
            ks = id >> 2;
        }
    }
    const int bcol = bx * 128;

    // ---- per-lane constant source offsets ----
    // A: lane covers (row = 16*i + 2w + dlt, float m of the 32-float span),
    //    stored at LDS slot sig = m>>2; logical k-group g = sig ^ (row&7).
    const int dlt = lane >> 5;               // 0/1
    const int m   = lane & 31;
    const int rw7 = (2 * w + dlt) & 7;       // == row&7 for every instr i
    const int ag  = (m >> 2) ^ rw7;          // logical k-group this lane fetches
    const size_t a_off = (size_t)(2 * w + dlt) * KTOT + ag * 4 + (m & 3);
    // B: lane covers k = 16*i + 2w + dlt, col-quad m
    const size_t b_off = (size_t)(2 * w + dlt) * NCOLS + bcol + m * 4;

    f32x4 acc[4][4];
    #pragma unroll
    for (int i = 0; i < 4; ++i)
        #pragma unroll
        for (int j = 0; j < 4; ++j)
            acc[i][j] = (f32x4){0.f, 0.f, 0.f, 0.f};

    const int s0 = ks * steps_per;
    int s1 = s0 + steps_per;
    if (s1 > NSTEPS) s1 = NSTEPS;

    auto issue_step = [&](int s, int buf) {
        // A: 16 x dword (4B) -> LDS [row][32] fp32, source-swizzled, cached
        const float* ap = x + a_off + (size_t)s * 32;
        #pragma unroll
        for (int i = 0; i < 16; ++i) {
            const float* gp = ap + (size_t)i * 16 * KTOT;
            char* lp = (char*)&Albuf[buf][0] + (i * 8 + w) * 256;   // wave-uniform
            __builtin_amdgcn_global_load_lds(
                (const __attribute__((address_space(1))) unsigned int*)(const void*)gp,
                (__attribute__((address_space(3))) unsigned int*)(void*)lp, 4, 0, 0);
        }
        // B: 2 x dwordx4 -> LDS [k][128] fp32, linear, NON-TEMPORAL
        const float* bp = W1 + b_off + (size_t)s * 32 * NCOLS;
        #pragma unroll
        for (int i = 0; i < 2; ++i) {
            const float* gp = bp + (size_t)i * 16 * NCOLS;
            char* lp = (char*)&Bbuf[buf][0] + (i * 512 + w * 64) * 16;  // wave-uniform
            __builtin_amdgcn_global_load_lds(
                (const __attribute__((address_space(1))) unsigned int*)(const void*)gp,
                (__attribute__((address_space(3))) unsigned int*)(void*)lp, 16, 0, AUX_NT);
        }
    };

    auto compute = [&](int buf) {
        const int rc = lane & 15, ko = lane >> 4;
        // B fragments: 8 strided b32 reads per frag, cvt -> bf16x8
        bf16x8 bq[4];
        #pragma unroll
        for (int ni = 0; ni < 4; ++ni) {
            const int colL = wn * 64 + ni * 16 + rc;
            float bf[8];
            #pragma unroll
            for (int j = 0; j < 8; ++j)
                bf[j] = Bbuf[buf][(ko * 8 + j) * 128 + colL];
            bq[ni] = pack8(bf);
        }
        // A fragments: two swizzled b128 reads per frag (slots sig, sig^1)
        const int soff = ((2 * ko) ^ (rc & 7)) * 16;   // row&7 == rc&7 here
        #pragma unroll
        for (int mi = 0; mi < 4; ++mi) {
            const int ab = (wm * 64 + mi * 16 + rc) * 128;   // row byte base
            float afv[8];
            *(f32x4*)&afv[0] = *(const f32x4*)((const char*)&Albuf[buf][0] + ab + soff);
            *(f32x4*)&afv[4] = *(const f32x4*)((const char*)&Albuf[buf][0] + ab + (soff ^ 16));
            const bf16x8 af = pack8(afv);
            #pragma unroll
            for (int ni = 0; ni < 4; ++ni)
                acc[mi][ni] = __builtin_amdgcn_mfma_f32_16x16x32_bf16(
                    af, bq[ni], acc[mi][ni], 0, 0, 0);
        }
    };

    // ---- pipelined main loop over FULL steps ----
    const int s1f  = (s1 < FSTEP) ? s1 : FSTEP;
    const int nfull = s1f - s0;
    if (nfull > 0) {
        issue_step(s0, 0);
        if (nfull > 1) issue_step(s0 + 1, 1);
        for (int t = 0; t < nfull; ++t) {
            if (t + 1 < nfull) { asm volatile("s_waitcnt vmcnt(18)" ::: "memory"); }
            else               { asm volatile("s_waitcnt vmcnt(0)"  ::: "memory"); }
            __builtin_amdgcn_s_barrier();
            __builtin_amdgcn_sched_barrier(0);
            compute(t % 3);
            if (t + 2 < nfull) issue_step(s0 + t + 2, (t + 2) % 3);
        }
    }

    // ---- tail: the single partial step (only the last split owns it) ----
    if (s1 > FSTEP) {
        const int buf = nfull % 3;   // differs from (nfull-1)%3 -> no hazard
        {   // A: guarded reg-staged, swizzled ds_write
            const int arow0 = tid >> 5, ak = tid & 31;
            const int gg = ak >> 2, jj = ak & 3;
            #pragma unroll
            for (int i = 0; i < 16; ++i) {
                const int row = arow0 + i * 16;
                const float v = (ak < (KTOT - FSTEP * 32))
                    ? x[(size_t)row * KTOT + (size_t)FSTEP * 32 + ak] : 0.f;
                Albuf[buf][row * 32 + (gg ^ (row & 7)) * 4 + jj] = v;
            }
        }
        {   // B: guarded
            const int bc2 = tid & 127, bkg2 = tid >> 7;
            #pragma unroll
            for (int j = 0; j < 8; ++j) {
                const int k = bkg2 * 8 + j;
                const float v = (k < (KTOT - FSTEP * 32))
                    ? W1[(size_t)(FSTEP * 32 + k) * NCOLS + bcol + bc2] : 0.f;
                Bbuf[buf][k * 128 + bc2] = v;
            }
        }
        __syncthreads();
        compute(buf);
    }

    // store partials; C/D layout: col = lane&15, row = (lane>>4)*4 + reg
    float* outp = part + (size_t)ks * MROWS * NCOLS;
    #pragma unroll
    for (int mi = 0; mi < 4; ++mi) {
        const int r0 = wm * 64 + mi * 16 + ((lane >> 4) * 4);
        #pragma unroll
        for (int ni = 0; ni < 4; ++ni) {
            const int c = bcol + wn * 64 + ni * 16 + (lane & 15);
            #pragma unroll
            for (int j = 0; j < 4; ++j)
                outp[(size_t)(r0 + j) * NCOLS + c] = acc[mi][ni][j];
        }
    }
}

// -------------------------------------------------------------------------
// Kernel 2: reduce split-K partials + b1 + relu -> h1 (LDS) -> u = h1@Wi
// -------------------------------------------------------------------------
__global__ __launch_bounds__(512) void reduce_u_kernel(
    const float* __restrict__ part, const float* __restrict__ b1,
    const float* __restrict__ Wi, float* __restrict__ u, int nks)
{
    __shared__ float h1[NCOLS];
    __shared__ f32x4 red[4][128];
    const int row = blockIdx.x;
    const int tid = threadIdx.x;
    const int c4  = tid & 127;
    const int kk  = tid >> 7;

    f32x4 sum = (f32x4){0.f, 0.f, 0.f, 0.f};
    for (int k = kk; k < nks; k += 4)
        sum += *(const f32x4*)&part[((size_t)k * MROWS + row) * NCOLS + c4 * 4];
    red[kk][c4] = sum;
    __syncthreads();

    if (tid < 128) {
        f32x4 t = red[0][tid] + red[1][tid] + red[2][tid] + red[3][tid];
        const f32x4 bb = *(const f32x4*)&b1[tid * 4];
        t += bb;
        #pragma unroll
        for (int j = 0; j < 4; ++j) h1[tid * 4 + j] = fmaxf(t[j], 0.f);
    }
    __syncthreads();

    const int wv = tid >> 6, lane = tid & 63;
    #pragma unroll
    for (int hh = 0; hh < 4; ++hh) {
        const int h = wv * 4 + hh;
        if (h < HDIM) {
            float p = 0.f;
            #pragma unroll
            for (int dd = 0; dd < 8; ++dd) {
                const int d = lane + dd * 64;
                p += h1[d] * Wi[d * HDIM + h];
            }
            #pragma unroll
            for (int off = 32; off; off >>= 1) p += __shfl_down(p, off);
            if (lane == 0) u[row * HDIM + h] = p;
        }
    }
}

// -------------------------------------------------------------------------
// Kernel 3: LTC recurrence (T=64, fp32, exact reference semantics) + head
// -------------------------------------------------------------------------
__global__ __launch_bounds__(64) void recur_kernel(
    const float* __restrict__ u, const float* __restrict__ Wr,
    const float* __restrict__ br, const float* __restrict__ Av,
    const float* __restrict__ tau, const float* __restrict__ W2,
    const float* __restrict__ b2, float* __restrict__ out)
{
    const int b = blockIdx.x;
    const int j = threadIdx.x;
    const bool act = j < HDIM;
    const int jj = act ? j : 0;

    float wr[HDIM];
    #pragma unroll
    for (int i = 0; i < HDIM; ++i) wr[i] = act ? Wr[i * HDIM + jj] : 0.f;
    const float brj = act ? br[jj] : 0.f;
    const float Aj  = act ? Av[jj] : 0.f;
    const float itj = act ? (1.f / tau[jj]) : 0.f;

    float uv[64];
    #pragma unroll
    for (int t = 0; t < 64; ++t)
        uv[t] = act ? u[(b * 64 + t) * HDIM + jj] : 0.f;

    float h = 0.f;
    #pragma unroll
    for (int t = 0; t < 64; ++t) {
        float a = uv[t] + brj;
        #pragma unroll
        for (int i = 0; i < HDIM; ++i)
            a += __shfl(h, i) * wr[i];
        const float ft = 1.f / (1.f + expf(-a));
        const float hn = (h + ft * Aj) / (1.f + itj + ft);
        h = act ? hn : 0.f;
    }

    const float r  = act ? fmaxf(h, 0.f) : 0.f;
    float p0 = act ? r * W2[jj * 2 + 0] : 0.f;
    float p1 = act ? r * W2[jj * 2 + 1] : 0.f;
    #pragma unroll
    for (int off = 32; off; off >>= 1) {
        p0 += __shfl_down(p0, off);
        p1 += __shfl_down(p1, off);
    }
    if (j == 0) {
        out[b * 2 + 0] = 1.f / (1.f + expf(-(p0 + b2[0])));
        out[b * 2 + 1] = 1.f / (1.f + expf(-(p1 + b2[1])));
    }
}

// -------------------------------------------------------------------------
extern "C" void kernel_launch(void* const* d_in, const int* in_sizes, int n_in,
                              void* d_out, int out_size, void* d_ws, size_t ws_size,
                              hipStream_t stream)
{
    (void)in_sizes; (void)n_in; (void)out_size;
    const float* x   = (const float*)d_in[0];
    const float* W1  = (const float*)d_in[1];
    const float* b1  = (const float*)d_in[2];
    const float* Wi  = (const float*)d_in[3];
    const float* Wr  = (const float*)d_in[4];
    const float* br  = (const float*)d_in[5];
    const float* Av  = (const float*)d_in[6];
    const float* tau = (const float*)d_in[7];
    const float* W2  = (const float*)d_in[8];
    const float* b2  = (const float*)d_in[9];
    float* out = (float*)d_out;

    // nks = 64 -> grid 256 blocks = 1 per CU (LDS 144KB forces 1/CU anyway)
    const size_t per_split = (size_t)MROWS * NCOLS * sizeof(float);   // 512 KiB
    int nks = 64;
    while (nks > 8 && (size_t)nks * per_split + (1 << 16) > ws_size) nks -= 8;
    const int steps_per = (NSTEPS + nks - 1) / nks;

    float* part = (float*)d_ws;
    float* u    = part + (size_t)nks * MROWS * NCOLS;

    gemm1_kernel<<<dim3(4 * nks), 512, 0, stream>>>(x, W1, part, steps_per, nks);
    reduce_u_kernel<<<dim3(MROWS), 512, 0, stream>>>(part, b1, Wi, u, nks);
    recur_kernel<<<dim3(4), 64, 0, stream>>>(u, Wr, br, Av, tau, W2, b2, out);
}